// Round 13
// baseline (378.032 us; speedup 1.0000x reference)
//
#include <hip/hip_runtime.h>
#include <hip/hip_cooperative_groups.h>
namespace cg = cooperative_groups;

#define N_NODES 20000
#define N_EDGES 640000
#define N_GRAPHS 64

// pool tiling (R11-proven)
#define NCHUNK 256
#define CHUNK_SZ 79    // 256*79 = 20224 >= 20000
#define GSPLIT 8
#define GSUB 8
#define NPOOLJOB (NCHUNK * GSPLIT)   // 2048

// fallback bucket (R11-proven)
#define BG_TILE 2048
#define NBG 313
#define SEGCAP 80
#define GR_CAP 768
#define NSLOT4 (NBG * SEGCAP / 4)

// fused bucket: 1024 tiles of 625 edges; mean 9.77, sigma 3.1 -> 48 = 12 sigma
#define FNBLK 1024
#define FBTILE 625
#define FSEGCAP 48
#define FNSLOT4 (FNBLK * FSEGCAP / 4)   // 12288 uint4 per graph

// ws layout (4B units), ws_size = 256 MiB:
//   Cdcol  [64][20000] f32     at 0
//   deg    [20000] f32         at 1,280,000
//   counts [64] f32            at 1,300,000
//   Y      [64][256] f32       at 1,300,064
//   part   [256][64][256] f32  at 1,316,448
//   bh     [313][64] u32       at 5,510,752   (fallback)
//   vals   [64][313][80] u32   at 5,530,784   (fallback)
//   bh2    [1024][64] u32      at 8,000,000   (fused)
//   vals2  [64][1024][48] u32  at 8,065,536   (fused; byte off %16==0)
// end = 11,211,264 words = 44.8 MB << 256 MiB
#define CD_OFF      0
#define DEG_OFF     1280000
#define CNT_OFF     1300000
#define Y_OFF       1300064
#define PART_OFF    1316448
#define BH_OFF      5510752
#define VALS_OFF    5530784
#define BH2_OFF     8000000
#define VALS2_OFF   8065536

#define FMA8(C0, C1, XV)                                          \
    acc[0].x = fmaf(C0.x, XV.x, acc[0].x); acc[0].y = fmaf(C0.x, XV.y, acc[0].y); \
    acc[0].z = fmaf(C0.x, XV.z, acc[0].z); acc[0].w = fmaf(C0.x, XV.w, acc[0].w); \
    acc[1].x = fmaf(C0.y, XV.x, acc[1].x); acc[1].y = fmaf(C0.y, XV.y, acc[1].y); \
    acc[1].z = fmaf(C0.y, XV.z, acc[1].z); acc[1].w = fmaf(C0.y, XV.w, acc[1].w); \
    acc[2].x = fmaf(C0.z, XV.x, acc[2].x); acc[2].y = fmaf(C0.z, XV.y, acc[2].y); \
    acc[2].z = fmaf(C0.z, XV.z, acc[2].z); acc[2].w = fmaf(C0.z, XV.w, acc[2].w); \
    acc[3].x = fmaf(C0.w, XV.x, acc[3].x); acc[3].y = fmaf(C0.w, XV.y, acc[3].y); \
    acc[3].z = fmaf(C0.w, XV.z, acc[3].z); acc[3].w = fmaf(C0.w, XV.w, acc[3].w); \
    acc[4].x = fmaf(C1.x, XV.x, acc[4].x); acc[4].y = fmaf(C1.x, XV.y, acc[4].y); \
    acc[4].z = fmaf(C1.x, XV.z, acc[4].z); acc[4].w = fmaf(C1.x, XV.w, acc[4].w); \
    acc[5].x = fmaf(C1.y, XV.x, acc[5].x); acc[5].y = fmaf(C1.y, XV.y, acc[5].y); \
    acc[5].z = fmaf(C1.y, XV.z, acc[5].z); acc[5].w = fmaf(C1.y, XV.w, acc[5].w); \
    acc[6].x = fmaf(C1.z, XV.x, acc[6].x); acc[6].y = fmaf(C1.z, XV.y, acc[6].y); \
    acc[6].z = fmaf(C1.z, XV.z, acc[6].z); acc[6].w = fmaf(C1.z, XV.w, acc[6].w); \
    acc[7].x = fmaf(C1.w, XV.x, acc[7].x); acc[7].y = fmaf(C1.w, XV.y, acc[7].y); \
    acc[7].z = fmaf(C1.w, XV.z, acc[7].z); acc[7].w = fmaf(C1.w, XV.w, acc[7].w);

// ===================== fused cooperative kernel =====================
__global__ void fused_k(const float* __restrict__ x,
                        const int* __restrict__ ei,
                        const int* __restrict__ batch,
                        const float* __restrict__ W0, const float* __restrict__ b0,
                        const float* __restrict__ W1, const float* __restrict__ b1,
                        const float* __restrict__ W2, const float* __restrict__ b2,
                        float* __restrict__ out,
                        float* __restrict__ Cdcol, float* __restrict__ deg,
                        float* __restrict__ counts, float* __restrict__ Y,
                        float* __restrict__ part,
                        unsigned* __restrict__ bh2, unsigned* __restrict__ vals2) {
    cg::grid_group grid = cg::this_grid();
    const int t = threadIdx.x;
    const int blk = blockIdx.x;
    const int gsz = (int)gridDim.x;

    // ---------- phase 1: bucket edges by g = batch[src] (1024 jobs) ----------
    __shared__ unsigned hist[N_GRAPHS];
    __shared__ unsigned base[N_GRAPHS + 1];
    __shared__ unsigned lv[FBTILE];
    __shared__ unsigned char gidx[FBTILE + 3];
    for (int job = blk; job < FNBLK; job += gsz) {
        __syncthreads();
        if (t < N_GRAPHS) hist[t] = 0u;
        __syncthreads();
        const int e0 = job * FBTILE;
        unsigned pv[3], rnk[3], gg[3];
#pragma unroll
        for (int k = 0; k < 3; ++k) {
            int i = t + k * 256;
            if (i < FBTILE) {
                unsigned s = (unsigned)ei[e0 + i];
                unsigned d = (unsigned)ei[N_EDGES + e0 + i];
                unsigned g = (unsigned)batch[s];
                pv[k] = (s << 15) | d;
                gg[k] = g;
                rnk[k] = atomicAdd(&hist[g], 1u);
            } else gg[k] = 0xFFFFFFFFu;
        }
        __syncthreads();
        if (t == 0) {
            unsigned a = 0u; base[0] = 0u;
            for (int g = 0; g < N_GRAPHS; ++g) { a += hist[g]; base[g + 1] = a; }
        }
        if (t < N_GRAPHS) {
            unsigned c = hist[t];
            bh2[job * N_GRAPHS + t] = (c > FSEGCAP) ? FSEGCAP : c;
        }
        __syncthreads();
        if (t < N_GRAPHS) {
            for (unsigned i = base[t]; i < base[t + 1]; ++i) gidx[i] = (unsigned char)t;
        }
#pragma unroll
        for (int k = 0; k < 3; ++k)
            if (gg[k] != 0xFFFFFFFFu) lv[base[gg[k]] + rnk[k]] = pv[k];
        __syncthreads();
        for (int i = t; i < FBTILE; i += 256) {
            unsigned g = gidx[i];
            unsigned slot = (unsigned)i - base[g];
            if (slot < FSEGCAP)
                vals2[(size_t)g * (FNBLK * FSEGCAP) + (unsigned)job * FSEGCAP + slot] = lv[i];
        }
        if (job == 0) {
            float4* y4 = (float4*)Y;
            for (int i = t; i < 64 * 64; i += 256) y4[i] = make_float4(0.f, 0.f, 0.f, 0.f);
        }
    }
    grid.sync();

    // ---------- phase 2: Cd column-sixteenths + deg + counts (1024 jobs) ----------
    __shared__ unsigned scnt2[FNBLK];      // 4 KB
    __shared__ unsigned dh2[625];          // 2.5 KB
    __shared__ unsigned sdeg2[GR_CAP];     // 3 KB
    __shared__ int s_lo, s_hi;
    for (int job = blk; job < FNBLK; job += gsz) {
        __syncthreads();
        const int g = job >> 4;
        const int six = job & 15;
        const int d0 = six * 1250;
        for (int i = t; i < FNBLK; i += 256) scnt2[i] = bh2[i * N_GRAPHS + g];
        for (int i = t; i < 625; i += 256) dh2[i] = 0u;
        if (six == 0) {
            for (int i = t; i < GR_CAP; i += 256) sdeg2[i] = 0u;
            if (t == 0) {
                int lo = 0, hi = N_NODES;
                while (lo < hi) { int m = (lo + hi) >> 1; if (batch[m] < g) lo = m + 1; else hi = m; }
                s_lo = lo;
                int lo2 = lo; hi = N_NODES;
                while (lo2 < hi) { int m = (lo2 + hi) >> 1; if (batch[m] < g + 1) lo2 = m + 1; else hi = m; }
                s_hi = lo2;
            }
        }
        __syncthreads();
        const int lo = (six == 0) ? s_lo : 0;
        const uint4* v4 = (const uint4*)(vals2 + (size_t)g * (FNBLK * FSEGCAP));
        for (int i = t; i < FNSLOT4; i += 256) {
            uint4 v = v4[i];
            unsigned w = (unsigned)i * 4u;
            unsigned seg = w / FSEGCAP;            // compiler magic-mul
            unsigned local = w - seg * FSEGCAP;
            unsigned c = scnt2[seg];
#define CD_ONE(VX, L)                                                             \
            if ((L) < c) {                                                        \
                int rd_ = (int)((VX) & 0x7FFFu) - d0;                             \
                if ((unsigned)rd_ < 1250u)                                        \
                    atomicAdd(&dh2[rd_ >> 1], 1u << ((rd_ & 1) * 16));            \
                if (six == 0) {                                                   \
                    int rs_ = (int)((VX) >> 15) - lo;                             \
                    if ((unsigned)rs_ < (unsigned)GR_CAP) atomicAdd(&sdeg2[rs_], 1u); \
                }                                                                 \
            }
            CD_ONE(v.x, local + 0u)
            CD_ONE(v.y, local + 1u)
            CD_ONE(v.z, local + 2u)
            CD_ONE(v.w, local + 3u)
#undef CD_ONE
        }
        __syncthreads();
        float2* outc = (float2*)(Cdcol + (size_t)g * N_NODES + d0);
        for (int w = t; w < 625; w += 256) {
            unsigned v = dh2[w];
            outc[w] = make_float2((float)(v & 0xFFFFu), (float)(v >> 16));
        }
        if (six == 0) {
            const int range = s_hi - lo;
            for (int i = t; i < range; i += 256) deg[lo + i] = (float)sdeg2[i];
            if (t == 0) {
                unsigned tot = 0;
                for (int i = 0; i < FNBLK; ++i) tot += scnt2[i];
                counts[g] = (float)tot;
            }
        }
    }
    grid.sync();

    // ---------- phase 3: pool (2048 jobs, R11 geometry) ----------
    __shared__ float4 sc4[CHUNK_SZ * 2];
    __shared__ float sdeg[CHUNK_SZ];
    __shared__ int   sbatch[CHUNK_SZ];
    __shared__ float4 red[2 * GSUB * 64];
    const int fg = t & 63;
    const int p  = t >> 6;
    for (int job = blk; job < NPOOLJOB; job += gsz) {
        __syncthreads();
        const int b = job & 255;
        const int j = job >> 8;
        const int n0 = b * CHUNK_SZ;
        int cnt = N_NODES - n0;
        if (cnt > CHUNK_SZ) cnt = CHUNK_SZ;
        if (cnt < 0) cnt = 0;

        float* sc = (float*)sc4;
        const float* cbase = Cdcol + (size_t)(j * GSUB) * N_NODES + n0;
#pragma unroll
        for (int k = 0; k < GSUB; ++k)
            for (int i = t; i < cnt; i += 256)
                sc[i * GSUB + k] = cbase[(size_t)k * N_NODES + i];
        if (j == 0) {
            for (int i = t; i < cnt; i += 256) {
                sdeg[i] = deg[n0 + i];
                sbatch[i] = batch[n0 + i];
            }
        }
        __syncthreads();

        const float4* xp = (const float4*)x + (size_t)n0 * 64 + fg;
#define XL(I) xp[(size_t)(I) * 64]
        float4 acc[GSUB];
#pragma unroll
        for (int k = 0; k < GSUB; ++k) acc[k] = make_float4(0.f, 0.f, 0.f, 0.f);

        if (j == 0) {
            float4 accs = make_float4(0.f, 0.f, 0.f, 0.f);
            int gprev = (p < cnt) ? sbatch[p] : 0;
            int i = p;
            float4 xn = make_float4(0.f, 0.f, 0.f, 0.f);
            if (i < cnt) xn = XL(i);
            for (; i < cnt; i += 4) {
                float4 xv = xn;
                if (i + 4 < cnt) xn = XL(i + 4);
                int g = sbatch[i];
                if (g != gprev) {
                    float* yr = Y + gprev * 256 + fg * 4;
                    atomicAdd(yr + 0, accs.x); atomicAdd(yr + 1, accs.y);
                    atomicAdd(yr + 2, accs.z); atomicAdd(yr + 3, accs.w);
                    accs = make_float4(0.f, 0.f, 0.f, 0.f);
                    gprev = g;
                }
                float dg = sdeg[i];
                accs.x = fmaf(dg, xv.x, accs.x); accs.y = fmaf(dg, xv.y, accs.y);
                accs.z = fmaf(dg, xv.z, accs.z); accs.w = fmaf(dg, xv.w, accs.w);
                float4 c0 = sc4[i * 2], c1 = sc4[i * 2 + 1];
                FMA8(c0, c1, xv)
            }
            if (p < cnt) {
                float* yr = Y + gprev * 256 + fg * 4;
                atomicAdd(yr + 0, accs.x); atomicAdd(yr + 1, accs.y);
                atomicAdd(yr + 2, accs.z); atomicAdd(yr + 3, accs.w);
            }
        } else {
            int i = p;
            float4 xa, xb;
            if (i     < cnt) xa = XL(i);
            if (i + 4 < cnt) xb = XL(i + 4);
            for (; i + 4 < cnt; i += 8) {
                float4 y0 = xa, y1 = xb;
                if (i + 8  < cnt) xa = XL(i + 8);
                if (i + 12 < cnt) xb = XL(i + 12);
                { float4 c0 = sc4[i * 2],       c1 = sc4[i * 2 + 1];       FMA8(c0, c1, y0) }
                { float4 c0 = sc4[(i + 4) * 2], c1 = sc4[(i + 4) * 2 + 1]; FMA8(c0, c1, y1) }
            }
            for (; i < cnt; i += 4) {
                float4 xv = XL(i);
                float4 c0 = sc4[i * 2], c1 = sc4[i * 2 + 1];
                FMA8(c0, c1, xv)
            }
        }
#undef XL

        if (p >= 2) {
#pragma unroll
            for (int k = 0; k < GSUB; ++k) red[(p - 2) * (GSUB * 64) + k * 64 + fg] = acc[k];
        }
        __syncthreads();
        if (p < 2) {
#pragma unroll
            for (int k = 0; k < GSUB; ++k) {
                float4 v = red[p * (GSUB * 64) + k * 64 + fg];
                acc[k].x += v.x; acc[k].y += v.y; acc[k].z += v.z; acc[k].w += v.w;
            }
        }
        __syncthreads();
        if (p == 1) {
#pragma unroll
            for (int k = 0; k < GSUB; ++k) red[k * 64 + fg] = acc[k];
        }
        __syncthreads();
        if (p == 0) {
            float4* part4 = (float4*)part;
#pragma unroll
            for (int k = 0; k < GSUB; ++k) {
                float4 v = red[k * 64 + fg];
                acc[k].x += v.x; acc[k].y += v.y; acc[k].z += v.z; acc[k].w += v.w;
                part4[(size_t)(b * 64 + j * GSUB + k) * 64 + fg] = acc[k];
            }
        }
    }
    grid.sync();

    // ---------- phase 4: fused reduce + 3-layer chain (128 jobs) ----------
    __shared__ float m2[256];
    __shared__ float h2[128];
    for (int job = blk; job < 128; job += gsz) {
        __syncthreads();
        const int r = job;
        const int g = r & 63;
        const int half = (r >= 64) ? 128 : 0;
        float c = counts[g];
        float inv = 1.0f / fmaxf(c, 1.0f);
        float beta = c * inv;

        if (r < 64) {
            m2[t] = Y[r * 256 + t] * inv;
        } else {
            float s = 0.0f;
            for (int bb = 0; bb < NCHUNK; ++bb) s += part[(size_t)(bb * 64 + g) * 256 + t];
            m2[t] = s * inv;
        }
        __syncthreads();
        if (t < 128) {
            float s1 = 0.0f;
            for (int k = 0; k < 256; ++k) s1 += m2[k] * W0[k * 128 + t];
            s1 += beta * b0[t];
            out[g * 768 + 0 + half + t] = s1;
            h2[t] = s1;
        }
        __syncthreads();
        float s2 = 0.0f;
        if (t < 128) {
            for (int k = 0; k < 128; ++k) s2 += h2[k] * W1[k * 128 + t];
            s2 += beta * b1[t];
            out[g * 768 + 256 + half + t] = s2;
        }
        __syncthreads();
        if (t < 128) h2[t] = s2;
        __syncthreads();
        if (t < 128) {
            float s3 = 0.0f;
            for (int k = 0; k < 128; ++k) s3 += h2[k] * W2[k * 128 + t];
            s3 += beta * b2[t];
            out[g * 768 + 512 + half + t] = s3;
        }
    }
}

// ===================== fallback kernels (R11-proven) =====================
__global__ __launch_bounds__(256) void bucket_g_k(const int* __restrict__ ei,
                                                  const int* __restrict__ batch,
                                                  unsigned* __restrict__ vals,
                                                  unsigned* __restrict__ bh,
                                                  float* __restrict__ Y) {
    __shared__ unsigned hist[N_GRAPHS];
    __shared__ unsigned base[N_GRAPHS + 1];
    __shared__ unsigned lv[BG_TILE];
    __shared__ unsigned char gidx[BG_TILE];
    const int t = threadIdx.x;
    const int blk = blockIdx.x;
    if (t < N_GRAPHS) hist[t] = 0u;
    __syncthreads();

    const int e0 = blk * BG_TILE;
    const int ecnt = (e0 + BG_TILE <= N_EDGES) ? BG_TILE : (N_EDGES - e0);
    unsigned pv[8], rnk[8], gg[8];
#pragma unroll
    for (int k = 0; k < 8; ++k) {
        int i = t + k * 256;
        if (i < ecnt) {
            unsigned s = (unsigned)ei[e0 + i];
            unsigned d = (unsigned)ei[N_EDGES + e0 + i];
            unsigned g = (unsigned)batch[s];
            pv[k] = (s << 15) | d;
            gg[k] = g;
            rnk[k] = atomicAdd(&hist[g], 1u);
        } else gg[k] = 0xFFFFFFFFu;
    }
    __syncthreads();
    if (t == 0) {
        unsigned a = 0u; base[0] = 0u;
        for (int g = 0; g < N_GRAPHS; ++g) { a += hist[g]; base[g + 1] = a; }
    }
    if (t < N_GRAPHS) {
        unsigned c = hist[t];
        bh[blk * N_GRAPHS + t] = (c > SEGCAP) ? SEGCAP : c;
    }
    __syncthreads();
    if (t < N_GRAPHS) {
        for (unsigned i = base[t]; i < base[t + 1]; ++i) gidx[i] = (unsigned char)t;
    }
#pragma unroll
    for (int k = 0; k < 8; ++k)
        if (gg[k] != 0xFFFFFFFFu) lv[base[gg[k]] + rnk[k]] = pv[k];
    __syncthreads();
    for (int i = t; i < ecnt; i += 256) {
        unsigned g = gidx[i];
        unsigned slot = (unsigned)i - base[g];
        if (slot < SEGCAP)
            vals[((size_t)g * NBG + blk) * SEGCAP + slot] = lv[i];
    }
    if (blk == 0) {
        float4* y4 = (float4*)Y;
        for (int i = t; i < 64 * 64; i += 256) y4[i] = make_float4(0.f, 0.f, 0.f, 0.f);
    }
}

__global__ __launch_bounds__(1024) void cd_col_k(const unsigned* __restrict__ vals,
                                                 const unsigned* __restrict__ bh,
                                                 const int* __restrict__ batch,
                                                 float* __restrict__ Cdcol,
                                                 float* __restrict__ deg,
                                                 float* __restrict__ counts) {
    __shared__ unsigned scnt[NBG];
    __shared__ unsigned dh[2500];
    __shared__ unsigned sdeg[GR_CAP];
    __shared__ int s_lo, s_hi;
    const int t = threadIdx.x;
    const int g = blockIdx.x >> 2;
    const int q = blockIdx.x & 3;
    const int d0 = q * 5000;

    for (int i = t; i < 2500; i += 1024) dh[i] = 0u;
    if (t < NBG) scnt[t] = bh[t * N_GRAPHS + g];
    if (q == 0) {
        if (t < GR_CAP) sdeg[t] = 0u;
        if (t == 0) {
            int lo = 0, hi = N_NODES;
            while (lo < hi) { int m = (lo + hi) >> 1; if (batch[m] < g) lo = m + 1; else hi = m; }
            s_lo = lo;
            int lo2 = lo; hi = N_NODES;
            while (lo2 < hi) { int m = (lo2 + hi) >> 1; if (batch[m] < g + 1) lo2 = m + 1; else hi = m; }
            s_hi = lo2;
        }
    }
    __syncthreads();
    const int lo = (q == 0) ? s_lo : 0;

    const uint4* v4 = (const uint4*)(vals + (size_t)g * NBG * SEGCAP);
    for (int i = t; i < NSLOT4; i += 1024) {
        uint4 v = *(v4 + i);
        unsigned w = (unsigned)i * 4u;
        unsigned seg = w / SEGCAP;
        unsigned local = w - seg * SEGCAP;
        unsigned c = scnt[seg];
#define CD_ONE(VX, L)                                                            \
        if ((L) < c) {                                                           \
            int rd_ = (int)((VX) & 0x7FFFu) - d0;                                \
            if ((unsigned)rd_ < 5000u)                                           \
                atomicAdd(&dh[rd_ >> 1], 1u << ((rd_ & 1) * 16));                \
            if (q == 0) {                                                        \
                int rs_ = (int)((VX) >> 15) - lo;                                \
                if ((unsigned)rs_ < (unsigned)GR_CAP) atomicAdd(&sdeg[rs_], 1u); \
            }                                                                    \
        }
        CD_ONE(v.x, local + 0u)
        CD_ONE(v.y, local + 1u)
        CD_ONE(v.z, local + 2u)
        CD_ONE(v.w, local + 3u)
#undef CD_ONE
    }
    __syncthreads();

    float2* outc = (float2*)(Cdcol + (size_t)g * N_NODES + d0);
    for (int w = t; w < 2500; w += 1024) {
        unsigned v = dh[w];
        outc[w] = make_float2((float)(v & 0xFFFFu), (float)(v >> 16));
    }
    if (q == 0) {
        const int range = s_hi - lo;
        for (int i = t; i < range; i += 1024) deg[lo + i] = (float)sdeg[i];
        if (t == 0) {
            unsigned tot = 0;
            for (int i = 0; i < NBG; ++i) tot += scnt[i];
            counts[g] = (float)tot;
        }
    }
}

__global__ __launch_bounds__(256) void pool_k(const float* __restrict__ x,
                                              const int* __restrict__ batch,
                                              const float* __restrict__ Cdcol,
                                              const float* __restrict__ deg,
                                              float* __restrict__ Y,
                                              float* __restrict__ part) {
    __shared__ float4 sc4[CHUNK_SZ * 2];
    __shared__ float sdeg[CHUNK_SZ];
    __shared__ int   sbatch[CHUNK_SZ];
    __shared__ float4 red[2 * GSUB * 64];

    const int t = threadIdx.x;
    const int fg = t & 63;
    const int p  = t >> 6;
    const int b = blockIdx.x & 255;
    const int j = blockIdx.x >> 8;
    const int n0 = b * CHUNK_SZ;
    int cnt = N_NODES - n0;
    if (cnt > CHUNK_SZ) cnt = CHUNK_SZ;
    if (cnt < 0) cnt = 0;

    float* sc = (float*)sc4;
    const float* cbase = Cdcol + (size_t)(j * GSUB) * N_NODES + n0;
#pragma unroll
    for (int k = 0; k < GSUB; ++k)
        for (int i = t; i < cnt; i += 256)
            sc[i * GSUB + k] = cbase[(size_t)k * N_NODES + i];
    if (j == 0) {
        for (int i = t; i < cnt; i += 256) {
            sdeg[i] = deg[n0 + i];
            sbatch[i] = batch[n0 + i];
        }
    }
    __syncthreads();

    const float4* xp = (const float4*)x + (size_t)n0 * 64 + fg;
#define XL(I) xp[(size_t)(I) * 64]
    float4 acc[GSUB];
#pragma unroll
    for (int k = 0; k < GSUB; ++k) acc[k] = make_float4(0.f, 0.f, 0.f, 0.f);

    if (j == 0) {
        float4 accs = make_float4(0.f, 0.f, 0.f, 0.f);
        int gprev = (p < cnt) ? sbatch[p] : 0;
        int i = p;
        float4 xn = make_float4(0.f, 0.f, 0.f, 0.f);
        if (i < cnt) xn = XL(i);
        for (; i < cnt; i += 4) {
            float4 xv = xn;
            if (i + 4 < cnt) xn = XL(i + 4);
            int g = sbatch[i];
            if (g != gprev) {
                float* yr = Y + gprev * 256 + fg * 4;
                atomicAdd(yr + 0, accs.x); atomicAdd(yr + 1, accs.y);
                atomicAdd(yr + 2, accs.z); atomicAdd(yr + 3, accs.w);
                accs = make_float4(0.f, 0.f, 0.f, 0.f);
                gprev = g;
            }
            float dg = sdeg[i];
            accs.x = fmaf(dg, xv.x, accs.x); accs.y = fmaf(dg, xv.y, accs.y);
            accs.z = fmaf(dg, xv.z, accs.z); accs.w = fmaf(dg, xv.w, accs.w);
            float4 c0 = sc4[i * 2], c1 = sc4[i * 2 + 1];
            FMA8(c0, c1, xv)
        }
        if (p < cnt) {
            float* yr = Y + gprev * 256 + fg * 4;
            atomicAdd(yr + 0, accs.x); atomicAdd(yr + 1, accs.y);
            atomicAdd(yr + 2, accs.z); atomicAdd(yr + 3, accs.w);
        }
    } else {
        int i = p;
        float4 xa, xb;
        if (i     < cnt) xa = XL(i);
        if (i + 4 < cnt) xb = XL(i + 4);
        for (; i + 4 < cnt; i += 8) {
            float4 y0 = xa, y1 = xb;
            if (i + 8  < cnt) xa = XL(i + 8);
            if (i + 12 < cnt) xb = XL(i + 12);
            { float4 c0 = sc4[i * 2],       c1 = sc4[i * 2 + 1];       FMA8(c0, c1, y0) }
            { float4 c0 = sc4[(i + 4) * 2], c1 = sc4[(i + 4) * 2 + 1]; FMA8(c0, c1, y1) }
        }
        for (; i < cnt; i += 4) {
            float4 xv = XL(i);
            float4 c0 = sc4[i * 2], c1 = sc4[i * 2 + 1];
            FMA8(c0, c1, xv)
        }
    }
#undef XL

    if (p >= 2) {
#pragma unroll
        for (int k = 0; k < GSUB; ++k) red[(p - 2) * (GSUB * 64) + k * 64 + fg] = acc[k];
    }
    __syncthreads();
    if (p < 2) {
#pragma unroll
        for (int k = 0; k < GSUB; ++k) {
            float4 v = red[p * (GSUB * 64) + k * 64 + fg];
            acc[k].x += v.x; acc[k].y += v.y; acc[k].z += v.z; acc[k].w += v.w;
        }
    }
    __syncthreads();
    if (p == 1) {
#pragma unroll
        for (int k = 0; k < GSUB; ++k) red[k * 64 + fg] = acc[k];
    }
    __syncthreads();
    if (p == 0) {
        float4* part4 = (float4*)part;
#pragma unroll
        for (int k = 0; k < GSUB; ++k) {
            float4 v = red[k * 64 + fg];
            acc[k].x += v.x; acc[k].y += v.y; acc[k].z += v.z; acc[k].w += v.w;
            part4[(size_t)(b * 64 + j * GSUB + k) * 64 + fg] = acc[k];
        }
    }
}

__global__ __launch_bounds__(256) void chain2_k(const float* __restrict__ Y,
                                                const float* __restrict__ part,
                                                const float* __restrict__ counts,
                                                const float* __restrict__ W0, const float* __restrict__ b0,
                                                const float* __restrict__ W1, const float* __restrict__ b1,
                                                const float* __restrict__ W2, const float* __restrict__ b2,
                                                float* __restrict__ out) {
    __shared__ float m[256];
    __shared__ float h[128];
    const int r = blockIdx.x;
    const int t = threadIdx.x;
    const int g = r & 63;
    const int half = (r >= 64) ? 128 : 0;

    float c = counts[g];
    float inv = 1.0f / fmaxf(c, 1.0f);
    float beta = c * inv;

    if (r < 64) {
        m[t] = Y[r * 256 + t] * inv;
    } else {
        float s = 0.0f;
        for (int bb = 0; bb < NCHUNK; ++bb) s += part[(size_t)(bb * 64 + g) * 256 + t];
        m[t] = s * inv;
    }
    __syncthreads();

    if (t < 128) {
        float s1 = 0.0f;
        for (int k = 0; k < 256; ++k) s1 += m[k] * W0[k * 128 + t];
        s1 += beta * b0[t];
        out[g * 768 + 0 + half + t] = s1;
        h[t] = s1;
    }
    __syncthreads();
    float s2 = 0.0f;
    if (t < 128) {
        for (int k = 0; k < 128; ++k) s2 += h[k] * W1[k * 128 + t];
        s2 += beta * b1[t];
        out[g * 768 + 256 + half + t] = s2;
    }
    __syncthreads();
    if (t < 128) h[t] = s2;
    __syncthreads();
    if (t < 128) {
        float s3 = 0.0f;
        for (int k = 0; k < 128; ++k) s3 += h[k] * W2[k * 128 + t];
        s3 += beta * b2[t];
        out[g * 768 + 512 + half + t] = s3;
    }
}

extern "C" void kernel_launch(void* const* d_in, const int* in_sizes, int n_in,
                              void* d_out, int out_size, void* d_ws, size_t ws_size,
                              hipStream_t stream) {
    const float* x     = (const float*)d_in[0];
    const int*   ei    = (const int*)d_in[1];
    const int*   batch = (const int*)d_in[2];
    const float* W0    = (const float*)d_in[3];
    const float* b0    = (const float*)d_in[4];
    const float* W1    = (const float*)d_in[5];
    const float* b1    = (const float*)d_in[6];
    const float* W2    = (const float*)d_in[7];
    const float* b2    = (const float*)d_in[8];
    float* out = (float*)d_out;

    float*    ws     = (float*)d_ws;
    float*    Cdcol  = ws + CD_OFF;
    float*    deg    = ws + DEG_OFF;
    float*    counts = ws + CNT_OFF;
    float*    Y      = ws + Y_OFF;
    float*    part   = ws + PART_OFF;
    unsigned* bh     = (unsigned*)(ws + BH_OFF);
    unsigned* vals   = (unsigned*)(ws + VALS_OFF);
    unsigned* bh2    = (unsigned*)(ws + BH2_OFF);
    unsigned* vals2  = (unsigned*)(ws + VALS2_OFF);

    // size cooperative grid to what actually co-resides
    int occ = 0;
    hipError_t qe = hipOccupancyMaxActiveBlocksPerMultiprocessor(&occ, (const void*)fused_k, 256, 0);
    bool coop_ok = false;
    if (qe == hipSuccess && occ > 0) {
        int grid = occ * 256;                 // 256 CUs on MI355X
        if (grid > NPOOLJOB) grid = NPOOLJOB;
        void* args[] = { (void*)&x, (void*)&ei, (void*)&batch,
                         (void*)&W0, (void*)&b0, (void*)&W1, (void*)&b1,
                         (void*)&W2, (void*)&b2, (void*)&out,
                         (void*)&Cdcol, (void*)&deg, (void*)&counts, (void*)&Y,
                         (void*)&part, (void*)&bh2, (void*)&vals2 };
        hipError_t le = hipLaunchCooperativeKernel((void*)fused_k, dim3(grid), dim3(256),
                                                   args, 0, stream);
        coop_ok = (le == hipSuccess);
    }
    if (!coop_ok) {
        // R11-proven 4-kernel fallback
        bucket_g_k<<<NBG, 256, 0, stream>>>(ei, batch, vals, bh, Y);
        cd_col_k<<<N_GRAPHS * 4, 1024, 0, stream>>>(vals, bh, batch, Cdcol, deg, counts);
        pool_k<<<NCHUNK * GSPLIT, 256, 0, stream>>>(x, batch, Cdcol, deg, Y, part);
        chain2_k<<<128, 256, 0, stream>>>(Y, part, counts, W0, b0, W1, b1, W2, b2, out);
    }
}

// Round 14
// 126.589 us; speedup vs baseline: 2.9863x; 2.9863x over previous
//
#include <hip/hip_runtime.h>

#define N_NODES 20000
#define N_EDGES 640000
#define N_GRAPHS 64

// pool tiling
#define NCHUNK 128
#define CHUNK_SZ 157   // 128*157 = 20096 >= 20000
#define GSPLIT 8       // graph-dim split: 8 blocks of 8 graphs each
#define GSUB 8

// graph-bucket sort (fixed per-(block,g) segments; no cursor, no memset)
#define BG_TILE 2048
#define NBG 313        // ceil(640000/2048)
#define SEGCAP 80      // per-(block,g) slots: mean ~32, sigma ~5.7 (R7/R8-proven)
#define GR_CAP 768     // max nodes per graph: mean 312.5, sigma 17.5 -> 26 sigma
#define NSLOT4 (NBG * SEGCAP / 4)   // 6260 uint4 per graph

// ws layout (4B units), ws_size = 256 MiB:
//   Cdcol  [64][20000] f32     at 0          per-graph dst-count column
//   deg    [20000] f32         at 1,280,000
//   counts [64] f32            at 1,300,000
//   Y      [64][256] f32       at 1,300,064  (zeroed by bucket_g_k blk0; pool atomics)
//   part   [128][64][256] f32  at 1,316,448
//   bh     [313][64] u32       at 3,413,600
//   vals   [64][313][80] u32   at 3,433,632
#define CD_OFF      0
#define DEG_OFF     1280000
#define CNT_OFF     1300000
#define Y_OFF       1300064
#define PART_OFF    1316448
#define BH_OFF      3413600
#define VALS_OFF    3433632

// bucket edges by g = batch[src]: LDS rank + block prefix-sum, reorder tile in
// LDS by g, write vals in contiguous per-g runs (coalesced; g via u8 LDS lookup).
__global__ __launch_bounds__(256) void bucket_g_k(const int* __restrict__ ei,
                                                  const int* __restrict__ batch,
                                                  unsigned* __restrict__ vals,
                                                  unsigned* __restrict__ bh,
                                                  float* __restrict__ Y) {
    __shared__ unsigned hist[N_GRAPHS];
    __shared__ unsigned base[N_GRAPHS + 1];
    __shared__ unsigned lv[BG_TILE];          // 8 KB reorder tile
    __shared__ unsigned char gidx[BG_TILE];   // 2 KB: output index -> graph
    const int t = threadIdx.x;
    const int blk = blockIdx.x;
    if (t < N_GRAPHS) hist[t] = 0u;
    __syncthreads();

    const int e0 = blk * BG_TILE;
    const int ecnt = (e0 + BG_TILE <= N_EDGES) ? BG_TILE : (N_EDGES - e0);
    unsigned pv[8], rnk[8], gg[8];
#pragma unroll
    for (int k = 0; k < 8; ++k) {
        int i = t + k * 256;
        if (i < ecnt) {
            unsigned s = (unsigned)ei[e0 + i];
            unsigned d = (unsigned)ei[N_EDGES + e0 + i];
            unsigned g = (unsigned)batch[s];
            pv[k] = (s << 15) | d;
            gg[k] = g;
            rnk[k] = atomicAdd(&hist[g], 1u);
        } else {
            gg[k] = 0xFFFFFFFFu;
        }
    }
    __syncthreads();
    if (t == 0) {                              // exclusive scan over 64 counters
        unsigned acc = 0u;
        base[0] = 0u;
        for (int g = 0; g < N_GRAPHS; ++g) { acc += hist[g]; base[g + 1] = acc; }
    }
    if (t < N_GRAPHS) {
        unsigned c = hist[t];
        bh[blk * N_GRAPHS + t] = (c > SEGCAP) ? SEGCAP : c;
    }
    __syncthreads();
    if (t < N_GRAPHS) {                        // fill gidx runs (parallel over g)
        unsigned b0 = base[t], b1 = base[t + 1];
        for (unsigned i = b0; i < b1; ++i) gidx[i] = (unsigned char)t;
    }
#pragma unroll
    for (int k = 0; k < 8; ++k) {
        if (gg[k] != 0xFFFFFFFFu) lv[base[gg[k]] + rnk[k]] = pv[k];
    }
    __syncthreads();
    // write out ordered tile: contiguous per-g runs -> coalesced global writes
    for (int i = t; i < ecnt; i += 256) {
        unsigned g = gidx[i];
        unsigned slot = (unsigned)i - base[g];
        if (slot < SEGCAP)
            vals[((size_t)g * NBG + blk) * SEGCAP + slot] = lv[i];
    }
    if (blk == 0) {   // zero pool's atomic target (replaces memset dispatch)
        float4* y4 = (float4*)Y;
        for (int i = t; i < 64 * 64; i += 256) y4[i] = make_float4(0.f, 0.f, 0.f, 0.f);
    }
}

// block = (g, dst-quarter), 1024 threads (16 waves): u16 LDS hist over 5000
// nodes, vals read as coalesced uint4 (SEGCAP%4==0; seg via magic-mul).
// q==0 also builds deg over g's contiguous src range + counts[g].
__global__ __launch_bounds__(1024) void cd_col_k(const unsigned* __restrict__ vals,
                                                 const unsigned* __restrict__ bh,
                                                 const int* __restrict__ batch,
                                                 float* __restrict__ Cdcol,
                                                 float* __restrict__ deg,
                                                 float* __restrict__ counts) {
    __shared__ unsigned scnt[NBG];
    __shared__ unsigned dh[2500];          // 10 KB: 5000 dst counts, u16 halves
    __shared__ unsigned sdeg[GR_CAP];      // 3 KB (q==0 only)
    __shared__ int s_lo, s_hi;
    const int t = threadIdx.x;
    const int g = blockIdx.x >> 2;
    const int q = blockIdx.x & 3;
    const int d0 = q * 5000;

    for (int i = t; i < 2500; i += 1024) dh[i] = 0u;
    if (t < NBG) scnt[t] = bh[t * N_GRAPHS + g];
    if (q == 0) {
        if (t < GR_CAP) sdeg[t] = 0u;
        if (t == 0) {
            int lo = 0, hi = N_NODES;                    // lower_bound(g)
            while (lo < hi) { int m = (lo + hi) >> 1; if (batch[m] < g) lo = m + 1; else hi = m; }
            s_lo = lo;
            int lo2 = lo; hi = N_NODES;                  // lower_bound(g+1)
            while (lo2 < hi) { int m = (lo2 + hi) >> 1; if (batch[m] < g + 1) lo2 = m + 1; else hi = m; }
            s_hi = lo2;
        }
    }
    __syncthreads();
    const int lo = (q == 0) ? s_lo : 0;

    const uint4* v4 = (const uint4*)(vals + (size_t)g * NBG * SEGCAP);
    for (int i = t; i < NSLOT4; i += 1024) {
        uint4 v = *(v4 + i);
        unsigned w = (unsigned)i * 4u;
        unsigned seg = (unsigned)(((unsigned long long)w * 53687092ull) >> 32);  // w/80 exact
        unsigned local = w - seg * 80u;
        unsigned c = scnt[seg];
#define CD_ONE(VX, L)                                                            \
        if ((L) < c) {                                                           \
            int rd_ = (int)((VX) & 0x7FFFu) - d0;                                \
            if ((unsigned)rd_ < 5000u)                                           \
                atomicAdd(&dh[rd_ >> 1], 1u << ((rd_ & 1) * 16));                \
            if (q == 0) {                                                        \
                int rs_ = (int)((VX) >> 15) - lo;                                \
                if ((unsigned)rs_ < (unsigned)GR_CAP) atomicAdd(&sdeg[rs_], 1u); \
            }                                                                    \
        }
        CD_ONE(v.x, local + 0u)
        CD_ONE(v.y, local + 1u)
        CD_ONE(v.z, local + 2u)
        CD_ONE(v.w, local + 3u)
#undef CD_ONE
    }
    __syncthreads();

    float2* outc = (float2*)(Cdcol + (size_t)g * N_NODES + d0);
    for (int w = t; w < 2500; w += 1024) {
        unsigned v = dh[w];
        outc[w] = make_float2((float)(v & 0xFFFFu), (float)(v >> 16));
    }
    if (q == 0) {
        const int range = s_hi - lo;
        for (int i = t; i < range; i += 1024) deg[lo + i] = (float)sdeg[i];
        if (t == 0) {
            unsigned tot = 0;
            for (int i = 0; i < NBG; ++i) tot += scnt[i];
            counts[g] = (float)tot;
        }
    }
}

#define FMA8(C0, C1, XV)                                          \
    acc[0].x = fmaf(C0.x, XV.x, acc[0].x); acc[0].y = fmaf(C0.x, XV.y, acc[0].y); \
    acc[0].z = fmaf(C0.x, XV.z, acc[0].z); acc[0].w = fmaf(C0.x, XV.w, acc[0].w); \
    acc[1].x = fmaf(C0.y, XV.x, acc[1].x); acc[1].y = fmaf(C0.y, XV.y, acc[1].y); \
    acc[1].z = fmaf(C0.y, XV.z, acc[1].z); acc[1].w = fmaf(C0.y, XV.w, acc[1].w); \
    acc[2].x = fmaf(C0.z, XV.x, acc[2].x); acc[2].y = fmaf(C0.z, XV.y, acc[2].y); \
    acc[2].z = fmaf(C0.z, XV.z, acc[2].z); acc[2].w = fmaf(C0.z, XV.w, acc[2].w); \
    acc[3].x = fmaf(C0.w, XV.x, acc[3].x); acc[3].y = fmaf(C0.w, XV.y, acc[3].y); \
    acc[3].z = fmaf(C0.w, XV.z, acc[3].z); acc[3].w = fmaf(C0.w, XV.w, acc[3].w); \
    acc[4].x = fmaf(C1.x, XV.x, acc[4].x); acc[4].y = fmaf(C1.x, XV.y, acc[4].y); \
    acc[4].z = fmaf(C1.x, XV.z, acc[4].z); acc[4].w = fmaf(C1.x, XV.w, acc[4].w); \
    acc[5].x = fmaf(C1.y, XV.x, acc[5].x); acc[5].y = fmaf(C1.y, XV.y, acc[5].y); \
    acc[5].z = fmaf(C1.y, XV.z, acc[5].z); acc[5].w = fmaf(C1.y, XV.w, acc[5].w); \
    acc[6].x = fmaf(C1.z, XV.x, acc[6].x); acc[6].y = fmaf(C1.z, XV.y, acc[6].y); \
    acc[6].z = fmaf(C1.z, XV.z, acc[6].z); acc[6].w = fmaf(C1.z, XV.w, acc[6].w); \
    acc[7].x = fmaf(C1.w, XV.x, acc[7].x); acc[7].y = fmaf(C1.w, XV.y, acc[7].y); \
    acc[7].z = fmaf(C1.w, XV.z, acc[7].z); acc[7].w = fmaf(C1.w, XV.w, acc[7].w);

// pool: block = (chunk b, split j of 8 graphs). 4 waves = 4 node phases; node
// loop unrolled x4 with 4 independent x prefetches in flight; tree reduce.
__global__ __launch_bounds__(256) void pool_k(const float* __restrict__ x,
                                              const int* __restrict__ batch,
                                              const float* __restrict__ Cdcol,
                                              const float* __restrict__ deg,
                                              float* __restrict__ Y,
                                              float* __restrict__ part) {
    __shared__ float4 sc4[CHUNK_SZ * 2];      // 5 KB: [node][2] float4 (GSUB=8)
    __shared__ float sdeg[CHUNK_SZ];
    __shared__ int   sbatch[CHUNK_SZ];
    __shared__ float4 red[2 * GSUB * 64];     // 16 KB cross-phase reduce

    const int t = threadIdx.x;
    const int fg = t & 63;                    // float4 feature group
    const int p  = t >> 6;                    // phase == wave id
    const int b = blockIdx.x & 127;           // same chunk's 8 splits: same XCD mod 8
    const int j = blockIdx.x >> 7;
    const int n0 = b * CHUNK_SZ;
    const int cnt = (n0 + CHUNK_SZ <= N_NODES) ? CHUNK_SZ : (N_NODES - n0);

    // transpose-stage 8 Cd columns into [node][8] LDS layout
    float* sc = (float*)sc4;
    const float* cbase = Cdcol + (size_t)(j * GSUB) * N_NODES + n0;
#pragma unroll
    for (int k = 0; k < GSUB; ++k)
        for (int i = t; i < cnt; i += 256)
            sc[i * GSUB + k] = cbase[(size_t)k * N_NODES + i];
    if (j == 0) {
        for (int i = t; i < cnt; i += 256) {
            sdeg[i] = deg[n0 + i];
            sbatch[i] = batch[n0 + i];
        }
    }
    __syncthreads();

    const float4* xp = (const float4*)x + (size_t)n0 * 64 + fg;
#define XL(I) xp[(size_t)(I) * 64]
    float4 acc[GSUB];
#pragma unroll
    for (int k = 0; k < GSUB; ++k) acc[k] = make_float4(0.f, 0.f, 0.f, 0.f);

    if (j == 0) {
        // src pooling path (1/8 of blocks): prefetch-1 loop, wave-uniform flushes
        float4 accs = make_float4(0.f, 0.f, 0.f, 0.f);
        int gprev = (p < cnt) ? sbatch[p] : 0;
        int i = p;
        float4 xn = make_float4(0.f, 0.f, 0.f, 0.f);
        if (i < cnt) xn = XL(i);
        for (; i < cnt; i += 4) {
            float4 xv = xn;
            if (i + 4 < cnt) xn = XL(i + 4);
            int g = sbatch[i];                  // wave-uniform
            if (g != gprev) {                   // uniform branch
                float* yr = Y + gprev * 256 + fg * 4;
                atomicAdd(yr + 0, accs.x); atomicAdd(yr + 1, accs.y);
                atomicAdd(yr + 2, accs.z); atomicAdd(yr + 3, accs.w);
                accs = make_float4(0.f, 0.f, 0.f, 0.f);
                gprev = g;
            }
            float dg = sdeg[i];
            accs.x = fmaf(dg, xv.x, accs.x); accs.y = fmaf(dg, xv.y, accs.y);
            accs.z = fmaf(dg, xv.z, accs.z); accs.w = fmaf(dg, xv.w, accs.w);
            float4 c0 = sc4[i * 2], c1 = sc4[i * 2 + 1];
            FMA8(c0, c1, xv)
        }
        if (p < cnt) {
            float* yr = Y + gprev * 256 + fg * 4;
            atomicAdd(yr + 0, accs.x); atomicAdd(yr + 1, accs.y);
            atomicAdd(yr + 2, accs.z); atomicAdd(yr + 3, accs.w);
        }
    } else {
        // dst-only path: unroll x4, 4 loads in flight
        int i = p;
        float4 xa, xb, xc, xd;
        if (i      < cnt) xa = XL(i);
        if (i + 4  < cnt) xb = XL(i + 4);
        if (i + 8  < cnt) xc = XL(i + 8);
        if (i + 12 < cnt) xd = XL(i + 12);
        for (; i + 12 < cnt; i += 16) {
            float4 y0 = xa, y1 = xb, y2 = xc, y3 = xd;
            if (i + 16 < cnt) xa = XL(i + 16);
            if (i + 20 < cnt) xb = XL(i + 20);
            if (i + 24 < cnt) xc = XL(i + 24);
            if (i + 28 < cnt) xd = XL(i + 28);
            {
                float4 c0 = sc4[i * 2], c1 = sc4[i * 2 + 1];
                FMA8(c0, c1, y0)
            }
            {
                float4 c0 = sc4[(i + 4) * 2], c1 = sc4[(i + 4) * 2 + 1];
                FMA8(c0, c1, y1)
            }
            {
                float4 c0 = sc4[(i + 8) * 2], c1 = sc4[(i + 8) * 2 + 1];
                FMA8(c0, c1, y2)
            }
            {
                float4 c0 = sc4[(i + 12) * 2], c1 = sc4[(i + 12) * 2 + 1];
                FMA8(c0, c1, y3)
            }
        }
        for (; i < cnt; i += 4) {
            float4 xv = XL(i);
            float4 c0 = sc4[i * 2], c1 = sc4[i * 2 + 1];
            FMA8(c0, c1, xv)
        }
    }
#undef XL

    // cross-phase reduce 4 -> 2 -> 1 (lane-consecutive, conflict-free)
    if (p >= 2) {
#pragma unroll
        for (int k = 0; k < GSUB; ++k) red[(p - 2) * (GSUB * 64) + k * 64 + fg] = acc[k];
    }
    __syncthreads();
    if (p < 2) {
#pragma unroll
        for (int k = 0; k < GSUB; ++k) {
            float4 v = red[p * (GSUB * 64) + k * 64 + fg];
            acc[k].x += v.x; acc[k].y += v.y; acc[k].z += v.z; acc[k].w += v.w;
        }
    }
    __syncthreads();
    if (p == 1) {
#pragma unroll
        for (int k = 0; k < GSUB; ++k) red[k * 64 + fg] = acc[k];
    }
    __syncthreads();
    if (p == 0) {
        float4* part4 = (float4*)part;
#pragma unroll
        for (int k = 0; k < GSUB; ++k) {
            float4 v = red[k * 64 + fg];
            acc[k].x += v.x; acc[k].y += v.y; acc[k].z += v.z; acc[k].w += v.w;
            part4[(size_t)(b * 64 + j * GSUB + k) * 64 + fg] = acc[k];
        }
    }
}

// fused reduce + chain: 128 blocks x 256 threads. Dst-row blocks (r>=64)
// reduce their 128 part slabs directly; Y rows 64..127 never materialized.
__global__ __launch_bounds__(256) void chain2_k(const float* __restrict__ Y,
                                                const float* __restrict__ part,
                                                const float* __restrict__ counts,
                                                const float* __restrict__ W0, const float* __restrict__ b0,
                                                const float* __restrict__ W1, const float* __restrict__ b1,
                                                const float* __restrict__ W2, const float* __restrict__ b2,
                                                float* __restrict__ out) {
    __shared__ float m[256];
    __shared__ float h[128];
    const int r = blockIdx.x;
    const int t = threadIdx.x;
    const int g = r & 63;
    const int half = (r >= 64) ? 128 : 0;

    float c = counts[g];
    float inv = 1.0f / fmaxf(c, 1.0f);
    float beta = c * inv;

    if (r < 64) {
        m[t] = Y[r * 256 + t] * inv;
    } else {
        float s = 0.0f;
        for (int bb = 0; bb < NCHUNK; ++bb) s += part[(size_t)(bb * 64 + g) * 256 + t];
        m[t] = s * inv;
    }
    __syncthreads();

    if (t < 128) {
        float s1 = 0.0f;
        for (int k = 0; k < 256; ++k) s1 += m[k] * W0[k * 128 + t];
        s1 += beta * b0[t];
        out[g * 768 + 0 + half + t] = s1;
        h[t] = s1;
    }
    __syncthreads();
    float s2 = 0.0f;
    if (t < 128) {
        for (int k = 0; k < 128; ++k) s2 += h[k] * W1[k * 128 + t];
        s2 += beta * b1[t];
        out[g * 768 + 256 + half + t] = s2;
    }
    __syncthreads();
    if (t < 128) h[t] = s2;
    __syncthreads();
    if (t < 128) {
        float s3 = 0.0f;
        for (int k = 0; k < 128; ++k) s3 += h[k] * W2[k * 128 + t];
        s3 += beta * b2[t];
        out[g * 768 + 512 + half + t] = s3;
    }
}

extern "C" void kernel_launch(void* const* d_in, const int* in_sizes, int n_in,
                              void* d_out, int out_size, void* d_ws, size_t ws_size,
                              hipStream_t stream) {
    const float* x     = (const float*)d_in[0];
    const int*   ei    = (const int*)d_in[1];
    const int*   batch = (const int*)d_in[2];
    const float* W0    = (const float*)d_in[3];
    const float* b0    = (const float*)d_in[4];
    const float* W1    = (const float*)d_in[5];
    const float* b1    = (const float*)d_in[6];
    const float* W2    = (const float*)d_in[7];
    const float* b2    = (const float*)d_in[8];
    float* out = (float*)d_out;

    float*    ws     = (float*)d_ws;
    float*    Cdcol  = ws + CD_OFF;
    float*    deg    = ws + DEG_OFF;
    float*    counts = ws + CNT_OFF;
    float*    Y      = ws + Y_OFF;
    float*    part   = ws + PART_OFF;
    unsigned* bh     = (unsigned*)(ws + BH_OFF);
    unsigned* vals   = (unsigned*)(ws + VALS_OFF);

    bucket_g_k<<<NBG, 256, 0, stream>>>(ei, batch, vals, bh, Y);
    cd_col_k<<<N_GRAPHS * 4, 1024, 0, stream>>>(vals, bh, batch, Cdcol, deg, counts);
    pool_k<<<NCHUNK * GSPLIT, 256, 0, stream>>>(x, batch, Cdcol, deg, Y, part);
    chain2_k<<<128, 256, 0, stream>>>(Y, part, counts, W0, b0, W1, b1, W2, b2, out);
}